// Round 5
// baseline (685.323 us; speedup 1.0000x reference)
//
#include <hip/hip_runtime.h>

#define NNODE 1024
#define NPT   512
#define MPT   128
#define ETOT  16384

// ---------------------------------------------------------------------------
// Workspace layout (floats):
//  f0   @ 0        : 1024*32      = 32768
//  f1   @ 32768    : 1024*96      = 98304
//  hh   @ 131072   : 4*16384*32   = 2097152   [p][e][k]
//  acc0 @ 2228224  : 1024*32      = 32768
//  acc1 @ 2260992  : 1024*96      = 98304
//  deg  @ 2359296  : 1024
// ---------------------------------------------------------------------------

__global__ void zero_kernel(float* __restrict__ p) {
    const int i = blockIdx.x * 256 + threadIdx.x;   // 129*256 = 33024 float4s
    if (i < 33024) ((float4*)p)[i] = make_float4(0.f, 0.f, 0.f, 0.f);
}

// --------------------------- three_nn + interpolation ----------------------
__global__ void interp_kernel(const float* __restrict__ h0, const float* __restrict__ h1,
                              const float* __restrict__ uph0, const float* __restrict__ uph1,
                              const float* __restrict__ xyz, const float* __restrict__ xyzp,
                              float* __restrict__ f0, float* __restrict__ f1) {
    __shared__ float sd2[128];
    __shared__ float sw[3];
    __shared__ int   sidx[3];
    const int n = blockIdx.x;          // node
    const int t = threadIdx.x;         // 0..127
    const int b = n >> 9;              // batch (N=512)
    const float x = xyz[n*3+0], y = xyz[n*3+1], z = xyz[n*3+2];
    const float* pb = &xyzp[(b*MPT + t)*3];
    const float dx = x - pb[0], dy = y - pb[1], dz = z - pb[2];
    sd2[t] = dx*dx + dy*dy + dz*dz;
    __syncthreads();
    if (t == 0) {
        float bd0 = 3.4e38f, bd1 = 3.4e38f, bd2 = 3.4e38f;
        int   i0 = 0, i1 = 0, i2 = 0;
        for (int i = 0; i < 128; ++i) {
            const float d = sd2[i];
            if (d < bd0)      { bd2 = bd1; i2 = i1; bd1 = bd0; i1 = i0; bd0 = d; i0 = i; }
            else if (d < bd1) { bd2 = bd1; i2 = i1; bd1 = d;   i1 = i; }
            else if (d < bd2) { bd2 = d;   i2 = i; }
        }
        const float inv0 = 1.f / (fmaxf(bd0, 1e-10f) + 1e-8f);
        const float inv1 = 1.f / (fmaxf(bd1, 1e-10f) + 1e-8f);
        const float inv2 = 1.f / (fmaxf(bd2, 1e-10f) + 1e-8f);
        const float s = inv0 + inv1 + inv2;
        sw[0] = inv0 / s; sw[1] = inv1 / s; sw[2] = inv2 / s;
        sidx[0] = i0; sidx[1] = i1; sidx[2] = i2;
    }
    __syncthreads();
    const float w0 = sw[0], w1 = sw[1], w2 = sw[2];
    const int g0 = b*MPT + sidx[0], g1 = b*MPT + sidx[1], g2 = b*MPT + sidx[2];
    if (t < 32) {
        const int c = t;
        float v;
        if (c < 16) v = w0*uph0[g0*16+c] + w1*uph0[g1*16+c] + w2*uph0[g2*16+c];
        else        v = h0[n*16 + (c-16)];
        f0[n*32 + c] = v;
    } else {
        const int q = t - 32, c = q / 3, m = q - c*3;
        float v;
        if (c < 16) v = w0*uph1[(g0*16+c)*3+m] + w1*uph1[(g1*16+c)*3+m] + w2*uph1[(g2*16+c)*3+m];
        else        v = h1[(n*16 + (c-16))*3 + m];
        f1[n*96 + c*3 + m] = v;
    }
}

// --------------------------- radial trunk: hh[4][E][32] --------------------
__global__ void trunk_kernel(const float* __restrict__ r,
                             const float* __restrict__ w1, const float* __restrict__ b1,
                             const float* __restrict__ g1, const float* __restrict__ be1,
                             const float* __restrict__ w2, const float* __restrict__ b2,
                             const float* __restrict__ g2, const float* __restrict__ be2,
                             float* __restrict__ hh) {
    const int tid = blockIdx.x * 256 + threadIdx.x;   // 0..65535
    const int p = tid >> 14, e = tid & 16383;
    const float rv = r[e];
    float a[32];
    float mu = 0.f;
    #pragma unroll
    for (int o = 0; o < 32; ++o) { a[o] = w1[p*32+o]*rv + b1[p*32+o]; mu += a[o]; }
    mu *= (1.f/32.f);
    float var = 0.f;
    #pragma unroll
    for (int o = 0; o < 32; ++o) { const float d = a[o]-mu; var += d*d; }
    var *= (1.f/32.f);
    float rs = 1.f / sqrtf(var + 1e-5f);
    float h[32];
    #pragma unroll
    for (int o = 0; o < 32; ++o)
        h[o] = fmaxf((a[o]-mu)*rs*g1[p*32+o] + be1[p*32+o], 0.f);
    float a2[32];
    mu = 0.f;
    #pragma unroll
    for (int o = 0; o < 32; ++o) {
        float acc = b2[p*32+o];
        const float* wr = &w2[(p*32+o)*32];
        #pragma unroll
        for (int i = 0; i < 32; ++i) acc += wr[i]*h[i];
        a2[o] = acc; mu += acc;
    }
    mu *= (1.f/32.f);
    var = 0.f;
    #pragma unroll
    for (int o = 0; o < 32; ++o) { const float d = a2[o]-mu; var += d*d; }
    var *= (1.f/32.f);
    rs = 1.f / sqrtf(var + 1e-5f);
    float outv[32];
    #pragma unroll
    for (int o = 0; o < 32; ++o)
        outv[o] = fmaxf((a2[o]-mu)*rs*g2[p*32+o] + be2[p*32+o], 0.f);
    float4* hv = (float4*)&hh[tid*32];
    #pragma unroll
    for (int j = 0; j < 8; ++j)
        hv[j] = make_float4(outv[j*4+0], outv[j*4+1], outv[j*4+2], outv[j*4+3]);
}

// --------------------------- per-edge messages (lane = edge) ---------------
// All W3 row indices are wave-uniform (forced via readfirstlane) -> the
// compiler emits s_load + v_fmac with SGPR operand: W3 streams through the
// scalar cache (free broadcast), zero LDS in the hot loop.
__device__ __forceinline__ float dot32b(const float* __restrict__ wr,
                                        const float* __restrict__ h, float bias) {
    float a0 = bias, a1 = 0.f, a2 = 0.f, a3 = 0.f;
    #pragma unroll
    for (int k = 0; k < 32; k += 4) {
        a0 = fmaf(wr[k+0], h[k+0], a0);
        a1 = fmaf(wr[k+1], h[k+1], a1);
        a2 = fmaf(wr[k+2], h[k+2], a2);
        a3 = fmaf(wr[k+3], h[k+3], a3);
    }
    return (a0 + a1) + (a2 + a3);
}

__launch_bounds__(256, 2)
__global__ void msg_kernel(const float* __restrict__ hhg,
                           const float* __restrict__ f0g, const float* __restrict__ f1g,
                           const float* __restrict__ w3_00, const float* __restrict__ b3_00,
                           const float* __restrict__ w3_01, const float* __restrict__ b3_01,
                           const float* __restrict__ w3_10, const float* __restrict__ b3_10,
                           const float* __restrict__ w3_11, const float* __restrict__ b3_11,
                           const float* __restrict__ bas00g, const float* __restrict__ bas01g,
                           const float* __restrict__ bas10g, const float* __restrict__ bas11g,
                           const int* __restrict__ esrc, const int* __restrict__ edst,
                           float* __restrict__ acc0, float* __restrict__ acc1,
                           float* __restrict__ deg) {
    const int lane = threadIdx.x & 63;
    // Force wave-uniform values into SGPRs: all lanes of a wave compute the
    // same W, so readfirstlane is value-preserving but makes uniformity
    // *provable* (otherwise W3 addressing falls back to vector loads).
    const int W = __builtin_amdgcn_readfirstlane(blockIdx.x * 4 + (threadIdx.x >> 6));
    const int g = W / 7;                                  // 64-edge group, 0..255
    const int q = W - g * 7;                              // quantum 0..6
    const int e = (g << 6) + lane;
    const int s = esrc[e];
    const int d = edst[e];

    float hh[32];
    {   // this quantum's pair index: q<2 -> q, q==2 -> 2, q>=3 -> 3
        const int p = (q < 2) ? q : ((q == 2) ? 2 : 3);
        const float4* hv = (const float4*)&hhg[((p << 14) + e) << 5];
        #pragma unroll
        for (int j = 0; j < 8; ++j) {
            float4 v = hv[j];
            hh[j*4] = v.x; hh[j*4+1] = v.y; hh[j*4+2] = v.z; hh[j*4+3] = v.w;
        }
    }

    if (q < 2) {
        // P0 (q==0): msg0[o] += sum_c R00[o][c] * bas00 * src0[c]
        // P1 (q==1): S01[o]  = sum_c R01[o][c] * src0[c]; msg1[o][m] = S01[o]*bas01[m]
        const float* hw = (q == 0) ? w3_00 : w3_01;
        const float* hb = (q == 0) ? b3_00 : b3_01;
        const float scale = (q == 0) ? bas00g[e] : 1.0f;
        if (q == 0) atomicAdd(&deg[d], 1.0f);
        float acc[32];
        #pragma unroll
        for (int o = 0; o < 32; ++o) acc[o] = 0.f;
        float srcv = f0g[s << 5];
        #pragma unroll 1
        for (int c = 0; c < 32; ++c) {
            const float nxt = (c < 31) ? f0g[(s << 5) + c + 1] : 0.f;
            const float pre = scale * srcv;
            #pragma unroll
            for (int o = 0; o < 32; ++o) {
                const int row = (o << 5) + c;                       // wave-uniform (SGPR)
                const float R = dot32b(&hw[row << 5], hh, hb[row]);
                acc[o] = fmaf(R, pre, acc[o]);
            }
            srcv = nxt;
        }
        if (q == 0) {
            #pragma unroll
            for (int o = 0; o < 32; ++o) atomicAdd(&acc0[(d << 5) + o], acc[o]);
        } else {
            const float bm0 = bas01g[e*3], bm1 = bas01g[e*3+1], bm2 = bas01g[e*3+2];
            #pragma unroll
            for (int o = 0; o < 32; ++o) {
                const int base = ((d << 5) + o) * 3;
                atomicAdd(&acc1[base+0], acc[o] * bm0);
                atomicAdd(&acc1[base+1], acc[o] * bm1);
                atomicAdd(&acc1[base+2], acc[o] * bm2);
            }
        }
    } else if (q == 2) {
        // P2: msg0[o] += sum_c R10[o][c] * (sum_n bas10[n]*src1[c][n])
        const float bn0 = bas10g[e*3], bn1 = bas10g[e*3+1], bn2 = bas10g[e*3+2];
        float acc[32];
        #pragma unroll
        for (int o = 0; o < 32; ++o) acc[o] = 0.f;
        float s0 = f1g[s*96+0], s1v = f1g[s*96+1], s2 = f1g[s*96+2];
        #pragma unroll 1
        for (int c = 0; c < 32; ++c) {
            float n0 = 0.f, n1 = 0.f, n2 = 0.f;
            if (c < 31) { n0 = f1g[s*96+c*3+3]; n1 = f1g[s*96+c*3+4]; n2 = f1g[s*96+c*3+5]; }
            const float pre = bn0*s0 + bn1*s1v + bn2*s2;
            #pragma unroll
            for (int o = 0; o < 32; ++o) {
                const int row = (o << 5) + c;                       // wave-uniform (SGPR)
                const float R = dot32b(&w3_10[row << 5], hh, b3_10[row]);
                acc[o] = fmaf(R, pre, acc[o]);
            }
            s0 = n0; s1v = n1; s2 = n2;
        }
        #pragma unroll
        for (int o = 0; o < 32; ++o) atomicAdd(&acc0[(d << 5) + o], acc[o]);
    } else {
        // P3, o-slice [ob, ob+8): msg1[o][m] += sum_{c,fi} R11[o][c*3+fi]*T11[c][m][fi]
        const int ob = (q - 3) << 3;                                // wave-uniform (SGPR)
        float bas[27];
        #pragma unroll
        for (int i = 0; i < 27; ++i) bas[i] = bas11g[e*27 + i];
        float acc[8][3];
        #pragma unroll
        for (int oo = 0; oo < 8; ++oo) { acc[oo][0] = 0.f; acc[oo][1] = 0.f; acc[oo][2] = 0.f; }
        float s0 = f1g[s*96+0], s1v = f1g[s*96+1], s2 = f1g[s*96+2];
        #pragma unroll 1
        for (int c = 0; c < 32; ++c) {
            float n0 = 0.f, n1 = 0.f, n2 = 0.f;
            if (c < 31) { n0 = f1g[s*96+c*3+3]; n1 = f1g[s*96+c*3+4]; n2 = f1g[s*96+c*3+5]; }
            #pragma unroll
            for (int fi = 0; fi < 3; ++fi) {
                const float t0 = bas[0+0*3+fi]*s0 + bas[0+1*3+fi]*s1v + bas[0+2*3+fi]*s2;
                const float t1 = bas[9+0*3+fi]*s0 + bas[9+1*3+fi]*s1v + bas[9+2*3+fi]*s2;
                const float t2 = bas[18+0*3+fi]*s0 + bas[18+1*3+fi]*s1v + bas[18+2*3+fi]*s2;
                #pragma unroll
                for (int oo = 0; oo < 8; ++oo) {
                    const int row = (ob + oo)*96 + c*3 + fi;        // wave-uniform (SGPR)
                    const float R = dot32b(&w3_11[row << 5], hh, b3_11[row]);
                    acc[oo][0] = fmaf(R, t0, acc[oo][0]);
                    acc[oo][1] = fmaf(R, t1, acc[oo][1]);
                    acc[oo][2] = fmaf(R, t2, acc[oo][2]);
                }
            }
            s0 = n0; s1v = n1; s2 = n2;
        }
        #pragma unroll
        for (int oo = 0; oo < 8; ++oo) {
            const int base = ((d << 5) + ob + oo) * 3;
            atomicAdd(&acc1[base+0], acc[oo][0]);
            atomicAdd(&acc1[base+1], acc[oo][1]);
            atomicAdd(&acc1[base+2], acc[oo][2]);
        }
    }
}

// --------------------------- node epilogue: mean + self + GNormSE3 ---------
__launch_bounds__(256)
__global__ void epi_kernel(const float* __restrict__ acc0, const float* __restrict__ acc1,
                           const float* __restrict__ deg,
                           const float* __restrict__ f0, const float* __restrict__ f1,
                           const float* __restrict__ sw0, const float* __restrict__ sw1,
                           const float* __restrict__ g0v, const float* __restrict__ b0v,
                           const float* __restrict__ nw0, const float* __restrict__ nb0,
                           const float* __restrict__ g1v, const float* __restrict__ b1v,
                           const float* __restrict__ nw1, const float* __restrict__ nb1,
                           float* __restrict__ out) {
    __shared__ float s_sw0[1024], s_sw1[1024], s_nw0[1024], s_nw1[1024];
    __shared__ float s_act0[8][33], s_act1[8][33];
    const int tid = threadIdx.x;
    #pragma unroll
    for (int j = 0; j < 4; ++j) {
        s_sw0[tid + 256*j] = sw0[tid + 256*j];
        s_sw1[tid + 256*j] = sw1[tid + 256*j];
        s_nw0[tid + 256*j] = nw0[tid + 256*j];
        s_nw1[tid + 256*j] = nw1[tid + 256*j];
    }
    const int o = tid & 31, nl = tid >> 5;
    const int n = blockIdx.x * 8 + nl;
    const float dr = deg[n];
    const float dc = fmaxf(dr, 1.0f);
    float v0 = acc0[n*32 + o] / dc;
    float v1[3];
    #pragma unroll
    for (int m = 0; m < 3; ++m) v1[m] = acc1[(n*32 + o)*3 + m] / dc;
    __syncthreads();
    if (dr > 0.f) {   // self-interaction gate: identical to deg/deg_clamped
        #pragma unroll
        for (int c = 0; c < 32; ++c) {
            v0 += s_sw0[o*32 + c] * f0[n*32 + c];
            const float w1c = s_sw1[o*32 + c];
            #pragma unroll
            for (int m = 0; m < 3; ++m) v1[m] += w1c * f1[(n*32 + c)*3 + m];
        }
    }
    const float nrm0 = fmaxf(fabsf(v0), 1e-12f);
    const float nrm1 = fmaxf(sqrtf(v1[0]*v1[0] + v1[1]*v1[1] + v1[2]*v1[2]), 1e-12f);
    float mu0 = nrm0, mu1 = nrm1;
    #pragma unroll
    for (int msk = 16; msk >= 1; msk >>= 1) { mu0 += __shfl_xor(mu0, msk); mu1 += __shfl_xor(mu1, msk); }
    mu0 *= (1.f/32.f); mu1 *= (1.f/32.f);
    const float d0 = nrm0 - mu0, d1 = nrm1 - mu1;
    float s0 = d0*d0, s1 = d1*d1;
    #pragma unroll
    for (int msk = 16; msk >= 1; msk >>= 1) { s0 += __shfl_xor(s0, msk); s1 += __shfl_xor(s1, msk); }
    const float var0 = s0*(1.f/32.f), var1 = s1*(1.f/32.f);
    const float a0 = fmaxf(d0 / sqrtf(var0 + 1e-5f) * g0v[o] + b0v[o], 0.f);
    const float a1 = fmaxf(d1 / sqrtf(var1 + 1e-5f) * g1v[o] + b1v[o], 0.f);
    s_act0[nl][o] = a0; s_act1[nl][o] = a1;
    __syncthreads();
    float t0 = nb0[o], t1 = nb1[o];
    #pragma unroll
    for (int c = 0; c < 32; ++c) {
        t0 += s_act0[nl][c] * s_nw0[o*32 + c];
        t1 += s_act1[nl][c] * s_nw1[o*32 + c];
    }
    float4 ov;
    ov.x = t0 * (v0 / nrm0);
    ov.y = t1 * (v1[0] / nrm1);
    ov.z = t1 * (v1[1] / nrm1);
    ov.w = t1 * (v1[2] / nrm1);
    *(float4*)&out[(n*32 + o)*4] = ov;
}

// ---------------------------------------------------------------------------
extern "C" void kernel_launch(void* const* d_in, const int* in_sizes, int n_in,
                              void* d_out, int out_size, void* d_ws, size_t ws_size,
                              hipStream_t stream) {
    const float* h0    = (const float*)d_in[0];
    const float* h1    = (const float*)d_in[1];
    const float* uph0  = (const float*)d_in[2];
    const float* uph1  = (const float*)d_in[3];
    const float* xyz   = (const float*)d_in[4];
    const float* xyzp  = (const float*)d_in[5];
    const float* r     = (const float*)d_in[6];
    const float* bas00 = (const float*)d_in[7];
    const float* bas01 = (const float*)d_in[8];
    const float* bas10 = (const float*)d_in[9];
    const float* bas11 = (const float*)d_in[10];
    const float* rw1   = (const float*)d_in[11];
    const float* rb1   = (const float*)d_in[12];
    const float* rg1   = (const float*)d_in[13];
    const float* rbe1  = (const float*)d_in[14];
    const float* rw2   = (const float*)d_in[15];
    const float* rb2   = (const float*)d_in[16];
    const float* rg2   = (const float*)d_in[17];
    const float* rbe2  = (const float*)d_in[18];
    const float* w00   = (const float*)d_in[19];
    const float* b00   = (const float*)d_in[20];
    const float* w01   = (const float*)d_in[21];
    const float* b01   = (const float*)d_in[22];
    const float* w10   = (const float*)d_in[23];
    const float* b10   = (const float*)d_in[24];
    const float* w11   = (const float*)d_in[25];
    const float* b11   = (const float*)d_in[26];
    const float* sw0   = (const float*)d_in[27];
    const float* sw1   = (const float*)d_in[28];
    const float* g0    = (const float*)d_in[29];
    const float* bb0   = (const float*)d_in[30];
    const float* nw0   = (const float*)d_in[31];
    const float* nb0   = (const float*)d_in[32];
    const float* g1    = (const float*)d_in[33];
    const float* bb1   = (const float*)d_in[34];
    const float* nw1   = (const float*)d_in[35];
    const float* nb1   = (const float*)d_in[36];
    const int*   esrc  = (const int*)d_in[37];
    const int*   edst  = (const int*)d_in[38];

    float* ws   = (float*)d_ws;
    float* f0   = ws;
    float* f1   = ws + 32768;
    float* hh   = ws + 131072;
    float* acc0 = ws + 2228224;
    float* acc1 = ws + 2260992;
    float* degb = ws + 2359296;
    float* out  = (float*)d_out;

    zero_kernel<<<129, 256, 0, stream>>>(acc0);                    // zeros acc0|acc1|deg
    interp_kernel<<<1024, 128, 0, stream>>>(h0, h1, uph0, uph1, xyz, xyzp, f0, f1);
    trunk_kernel<<<256, 256, 0, stream>>>(r, rw1, rb1, rg1, rbe1, rw2, rb2, rg2, rbe2, hh);
    msg_kernel<<<448, 256, 0, stream>>>(hh, f0, f1, w00, b00, w01, b01, w10, b10, w11, b11,
                                        bas00, bas01, bas10, bas11, esrc, edst, acc0, acc1, degb);
    epi_kernel<<<128, 256, 0, stream>>>(acc0, acc1, degb, f0, f1, sw0, sw1,
                                        g0, bb0, nw0, nb0, g1, bb1, nw1, nb1, out);
}